// Round 12
// baseline (1592.944 us; speedup 1.0000x reference)
//
#include <hip/hip_runtime.h>
#include <hip/hip_bf16.h>

// RNN_80848464380442: B=64, S=2048, V=50257, E=128, H=256, C=2 (f32 in/out, x int32)
// Stage 1: xw[tok][sig(j)] = bU[j] + sum_e emb[x]*W  (fp16 to ws, sigma-permuted cols)
// Stage 2: MFMA scan, 4 blocks x 16 batch rows, 8 waves x 2 N-tiles (512 thr, 2 w/SIMD).
//          fp16; U in regs as B-frags; h double-buffered in LDS (PITCH=264, bank-balanced
//          b128 A-reads = intrinsic 8-way minimum); xw folded into MFMA C-input;
//          2-step prefetch ring; hoisted LDS pointers + literal buffer idx (imm offsets);
//          uniform xw offset on SALU; peeled tail (no clamp in main loop); lgkm barrier.
// Stage 3: logits + h output post-loop from LDS.
// sigma: j = 32w+16s+n  ->  p = 32w+2n+s

#define HB 256
#define EB 128
#define SB 2048
#define BB 64
#define TPB 32
#define ROWS 16
#define PITCH 264   // u16/row = 528 B; b128 reads: 8 lanes/4-bank group = balanced

typedef unsigned short u16;
typedef __attribute__((ext_vector_type(4))) float f32x4;
typedef __attribute__((ext_vector_type(8))) _Float16 f16x8;
typedef __attribute__((ext_vector_type(2))) __fp16 fp16x2_t;

__device__ __forceinline__ u16 f2h_bits(float f) {
    union { _Float16 h; u16 b; } x; x.h = (_Float16)f; return x.b;
}
__device__ __forceinline__ float h2f_bits(u16 b) {
    union { u16 b; _Float16 h; } x; x.b = b; return (float)x.h;
}
__device__ __forceinline__ float tanh_fast(float z) {
    float E = exp2f(z * 2.885390082f);             // e^(2z); tanh = 1 - 2/(e^2z + 1)
    return fmaf(-2.f, __builtin_amdgcn_rcpf(E + 1.f), 1.f);
}
__device__ __forceinline__ unsigned pkrtz(float a, float b) {
    fp16x2_t p = __builtin_amdgcn_cvt_pkrtz(a, b);
    return __builtin_bit_cast(unsigned, p);
}
// LDS-visibility barrier that does NOT drain vmcnt (keeps global prefetch in flight)
__device__ __forceinline__ void lds_barrier() {
    asm volatile("s_waitcnt lgkmcnt(0)" ::: "memory");
    __builtin_amdgcn_s_barrier();
    asm volatile("" ::: "memory");
}

__device__ __forceinline__ int sig(int j)    { return (j & 0xE0) | ((j & 15) << 1) | ((j >> 4) & 1); }
__device__ __forceinline__ int invsig(int p) { return (p & 0xE0) | ((p & 1) << 4) | ((p >> 1) & 15); }

// ---------------- Stage 1: embed + project (32 tokens per 256-thread block) --------
__global__ __launch_bounds__(256) void embed_proj(
    const int* __restrict__ x, const float* __restrict__ emb,
    const float* __restrict__ W, const float* __restrict__ bU,
    u16* __restrict__ xw)
{
    __shared__ __align__(16) float el[TPB][EB];   // 16 KB
    __shared__ int toks[TPB];

    const int tid = threadIdx.x;
    const long base = (long)blockIdx.x * TPB;

    if (tid < TPB) toks[tid] = x[base + tid];
    __syncthreads();

    for (int r = 0; r < TPB * EB / 256; ++r) {
        int i = tid + r * 256;
        int row = i >> 7, e = i & (EB - 1);
        int u = toks[row];
        el[row][e] = (u == 0) ? 0.f : emb[(size_t)u * EB + e];   // padding_idx=0
    }
    __syncthreads();

    const int j = tid;
    const int sj = sig(j);
    const float bu = bU[j];
    float acc[TPB];
    #pragma unroll
    for (int t = 0; t < TPB; ++t) acc[t] = bu;

    for (int e0 = 0; e0 < EB; e0 += 4) {
        float w0 = W[(e0 + 0) * HB + j];
        float w1 = W[(e0 + 1) * HB + j];
        float w2 = W[(e0 + 2) * HB + j];
        float w3 = W[(e0 + 3) * HB + j];
        #pragma unroll
        for (int t = 0; t < TPB; ++t) {
            float4 ev = *(const float4*)&el[t][e0];
            acc[t] = fmaf(ev.x, w0, acc[t]);
            acc[t] = fmaf(ev.y, w1, acc[t]);
            acc[t] = fmaf(ev.z, w2, acc[t]);
            acc[t] = fmaf(ev.w, w3, acc[t]);
        }
    }
    #pragma unroll
    for (int t = 0; t < TPB; ++t)
        xw[(base + t) * HB + sj] = f2h_bits(acc[t]);
}

// ---------------- Stage 2+3: MFMA scan, 4 blocks x 512 threads (8 waves) -----------
// CB is a LITERAL (0/1). Consume X (xw of the step being computed), optionally
// reissue X <- xw at uniform pointer xw + PFT*HB (SALU address path).
#define STEP_CORE(CB, X, DO_PF, PFT)                                               \
  {                                                                                \
    f32x4 acc0, acc1;                                                              \
    _Pragma("unroll")                                                              \
    for (int q = 0; q < 4; ++q) {                                                  \
        acc0[q] = h2f_bits((u16)(X[q] & 0xffffu));                                 \
        acc1[q] = h2f_bits((u16)(X[q] >> 16));                                     \
    }                                                                              \
    if (DO_PF) {                                                                   \
        const u16* xwp = xw + (size_t)(PFT) * HB;   /* uniform -> SALU */          \
        _Pragma("unroll")                                                          \
        for (int q = 0; q < 4; ++q)                                                \
            X[q] = *(const unsigned*)&xwp[gbase[q]];                               \
    }                                                                              \
    f16x8 Af[8];                                                                   \
    _Pragma("unroll")                                                              \
    for (int ks = 0; ks < 8; ++ks)                                                 \
        Af[ks] = *(const f16x8*)(aptr##CB + ks * 32);   /* imm offset ks*64B */    \
    _Pragma("unroll")                                                              \
    for (int ks = 0; ks < 8; ++ks) {                                               \
        acc0 = __builtin_amdgcn_mfma_f32_16x16x32_f16(Af[ks], Bf[0][ks], acc0, 0, 0, 0); \
        acc1 = __builtin_amdgcn_mfma_f32_16x16x32_f16(Af[ks], Bf[1][ks], acc1, 0, 0, 0); \
    }                                                                              \
    _Pragma("unroll")                                                              \
    for (int q = 0; q < 4; ++q) {                                                  \
        float th0 = tanh_fast(acc0[q]);                                            \
        float th1 = tanh_fast(acc1[q]);                                            \
        *(unsigned*)(wptr##CB + q * PITCH) = pkrtz(th0, th1);  /* imm offset */    \
    }                                                                              \
    lds_barrier();                                                                 \
  }
// wptr##CB: CB is the READ buffer; write goes to the OTHER buffer (wptr0 -> buf1 etc.)

__global__ __launch_bounds__(512, 2) void rnn_scan_mfma(
    const u16* __restrict__ xw, const float* __restrict__ U,
    const float* __restrict__ V, const float* __restrict__ bV,
    float* __restrict__ out)
{
    __shared__ __align__(16) u16 H[2][ROWS][PITCH];   // double-buffered h (fp16), sigma order

    const int tid  = threadIdx.x;
    const int lane = tid & 63;
    const int w    = tid >> 6;            // wave 0..7, owns N-tiles 2w, 2w+1
    const int b0   = blockIdx.x * ROWS;

    {   // zero both H buffers (incl. pad)
        unsigned* hz = (unsigned*)H;
        for (int i = tid; i < 2 * ROWS * PITCH / 2; i += 512) hz[i] = 0u;
    }

    const int n  = lane & 15;             // A-m / B-n / D-col
    const int kg = lane >> 4;             // 0..3

    // ---- B-frag preload via sigma^-1: Bf[s][ks], tile nt=2w+s, col j_out=nt*16+n ----
    f16x8 Bf[2][8];
    #pragma unroll
    for (int s = 0; s < 2; ++s) {
        const int col = (2 * w + s) * 16 + n;
        #pragma unroll
        for (int ks = 0; ks < 8; ++ks) {
            union { f16x8 v; u16 h[8]; } tmp;
            #pragma unroll
            for (int e = 0; e < 8; ++e) {
                const int p = ks * 32 + kg * 8 + e;          // storage k
                const int jin = invsig(p);                   // actual contraction j
                tmp.h[e] = f2h_bits(U[(size_t)jin * HB + col]);
            }
            Bf[s][ks] = tmp.v;
        }
    }

    // ---- hoisted pointers (loop-invariant; reads/writes use imm offsets) ----
    const int pbase = 32 * w + 2 * n;
    const u16* aptr0 = &H[0][n][kg * 8];          // A-frag base, read buffer 0
    const u16* aptr1 = &H[1][n][kg * 8];          // A-frag base, read buffer 1
    u16* wptr0 = &H[1][kg * 4][pbase];            // write target when reading buf 0
    u16* wptr1 = &H[0][kg * 4][pbase];            // write target when reading buf 1

    unsigned gbase[4];                            // per-lane xw u16 offsets (row part)
    unsigned XA[4], XB[4];
    #pragma unroll
    for (int q = 0; q < 4; ++q) {
        const int row = kg * 4 + q;
        gbase[q] = ((unsigned)(b0 + row) * SB) * HB + pbase;
        XA[q] = *(const unsigned*)&xw[gbase[q]];             // t = 0
        XB[q] = *(const unsigned*)&xw[gbase[q] + HB];        // t = 1
    }
    lds_barrier();

    // main loop: steps 0..SB-5, unconditional prefetch (max PFT = SB-3)
    for (int t = 0; t < SB - 4; t += 4) {
        STEP_CORE(0, XA, 1, t + 2);
        STEP_CORE(1, XB, 1, t + 3);
        STEP_CORE(0, XA, 1, t + 4);
        STEP_CORE(1, XB, 1, t + 5);
    }
    // tail: steps SB-4..SB-1 (XA = SB-4, XB = SB-3 on entry)
    STEP_CORE(0, XA, 1, SB - 2);
    STEP_CORE(1, XB, 1, SB - 1);
    STEP_CORE(0, XA, 0, 0);
    STEP_CORE(1, XB, 0, 0);

    // h output (f32 from fp16 H[0]; SB even -> final h in buffer 0)
    for (int i = tid; i < ROWS * HB; i += 512) {
        const int r = i >> 8, p = i & 255;
        out[BB * 2 + (size_t)(b0 + r) * HB + invsig(p)] = h2f_bits(H[0][r][p]);
    }

    // logits: first 256 threads = 16 rows x 16 partials
    if (tid < ROWS * 16) {
        const int r = tid >> 4, part = tid & 15;
        float s0 = 0.f, s1 = 0.f;
        #pragma unroll
        for (int i = 0; i < 16; ++i) {
            const int p = part * 16 + i;
            const int j = invsig(p);
            float hh = h2f_bits(H[0][r][p]);
            s0 = fmaf(hh, V[j * 2 + 0], s0);
            s1 = fmaf(hh, V[j * 2 + 1], s1);
        }
        #pragma unroll
        for (int o = 8; o > 0; o >>= 1) {
            s0 += __shfl_down(s0, o, 16);
            s1 += __shfl_down(s1, o, 16);
        }
        if (part == 0) {
            out[(size_t)(b0 + r) * 2 + 0] = s0 + bV[0];
            out[(size_t)(b0 + r) * 2 + 1] = s1 + bV[1];
        }
    }
}

extern "C" void kernel_launch(void* const* d_in, const int* in_sizes, int n_in,
                              void* d_out, int out_size, void* d_ws, size_t ws_size,
                              hipStream_t stream) {
    const int*   x   = (const int*)d_in[0];
    const float* emb = (const float*)d_in[1];
    const float* W   = (const float*)d_in[2];
    const float* U   = (const float*)d_in[3];
    const float* bU  = (const float*)d_in[4];
    const float* V   = (const float*)d_in[5];
    const float* bV  = (const float*)d_in[6];
    float* out = (float*)d_out;
    u16*   xw  = (u16*)d_ws;   // 64 MiB fp16 scratch, sigma-permuted columns

    embed_proj<<<BB * SB / TPB, 256, 0, stream>>>(x, emb, W, bU, xw);
    rnn_scan_mfma<<<BB / ROWS, 512, 0, stream>>>(xw, U, V, bV, out);
}

// Round 13
// 1386.271 us; speedup vs baseline: 1.1491x; 1.1491x over previous
//
#include <hip/hip_runtime.h>
#include <hip/hip_bf16.h>

// RNN_80848464380442: B=64, S=2048, V=50257, E=128, H=256, C=2 (f32 in/out, x int32)
// Stage 1: xw[tok][sig(j)] = bU[j] + sum_e emb[x]*W  (fp16 to ws, sigma-permuted cols)
// Stage 2: MFMA scan, 8 blocks x 8 batch rows (8 CUs), 8 waves x 2 N-tiles (512 thr).
//          fp16; U in regs as B-frags; h (8 rows) double-buffered in LDS; A-reads use
//          row n&7 -> lanes m,m+8 broadcast same address (free) -> 512B/instr, zero
//          excess bank conflict; D rows 8-15 are harmless duplicates (C-init dup'd,
//          writes masked to kg<2). xw folded into MFMA C; 2-step prefetch ring;
//          plain __syncthreads (R10-12 lesson: asm barrier blocks scheduling).
// Stage 3: logits + h output post-loop from LDS.
// sigma: j = 32w+16s+n  ->  p = 32w+2n+s

#define HB 256
#define EB 128
#define SB 2048
#define BB 64
#define TPB 32
#define ROWS 8
#define PITCH 264   // u16/row = 528 B; bank-group 4*(row+kg) mod 32 -> balanced

typedef unsigned short u16;
typedef __attribute__((ext_vector_type(4))) float f32x4;
typedef __attribute__((ext_vector_type(8))) _Float16 f16x8;

__device__ __forceinline__ u16 f2h_bits(float f) {
    union { _Float16 h; u16 b; } x; x.h = (_Float16)f; return x.b;
}
__device__ __forceinline__ float h2f_bits(u16 b) {
    union { u16 b; _Float16 h; } x; x.b = b; return (float)x.h;
}
__device__ __forceinline__ float tanh_fast(float z) {
    float E = __expf(z + z);                       // tanh = 1 - 2/(e^2z + 1)
    return fmaf(-2.f, __builtin_amdgcn_rcpf(E + 1.f), 1.f);
}

__device__ __forceinline__ int sig(int j)    { return (j & 0xE0) | ((j & 15) << 1) | ((j >> 4) & 1); }
__device__ __forceinline__ int invsig(int p) { return (p & 0xE0) | ((p & 1) << 4) | ((p >> 1) & 15); }

// ---------------- Stage 1: embed + project (32 tokens per 256-thread block) --------
__global__ __launch_bounds__(256) void embed_proj(
    const int* __restrict__ x, const float* __restrict__ emb,
    const float* __restrict__ W, const float* __restrict__ bU,
    u16* __restrict__ xw)
{
    __shared__ __align__(16) float el[TPB][EB];   // 16 KB
    __shared__ int toks[TPB];

    const int tid = threadIdx.x;
    const long base = (long)blockIdx.x * TPB;

    if (tid < TPB) toks[tid] = x[base + tid];
    __syncthreads();

    for (int r = 0; r < TPB * EB / 256; ++r) {
        int i = tid + r * 256;
        int row = i >> 7, e = i & (EB - 1);
        int u = toks[row];
        el[row][e] = (u == 0) ? 0.f : emb[(size_t)u * EB + e];   // padding_idx=0
    }
    __syncthreads();

    const int j = tid;
    const int sj = sig(j);
    const float bu = bU[j];
    float acc[TPB];
    #pragma unroll
    for (int t = 0; t < TPB; ++t) acc[t] = bu;

    for (int e0 = 0; e0 < EB; e0 += 4) {
        float w0 = W[(e0 + 0) * HB + j];
        float w1 = W[(e0 + 1) * HB + j];
        float w2 = W[(e0 + 2) * HB + j];
        float w3 = W[(e0 + 3) * HB + j];
        #pragma unroll
        for (int t = 0; t < TPB; ++t) {
            float4 ev = *(const float4*)&el[t][e0];
            acc[t] = fmaf(ev.x, w0, acc[t]);
            acc[t] = fmaf(ev.y, w1, acc[t]);
            acc[t] = fmaf(ev.z, w2, acc[t]);
            acc[t] = fmaf(ev.w, w3, acc[t]);
        }
    }
    #pragma unroll
    for (int t = 0; t < TPB; ++t)
        xw[(base + t) * HB + sj] = f2h_bits(acc[t]);
}

// ---------------- Stage 2+3: MFMA scan, 8 blocks x 512 threads (8 waves) -----------
// STEP(T, X): X holds step T's xw pair-words; init accs from X, reissue X <- T+2,
// broadcast A-reads (row n&7), 16 MFMAs (C-in = xw), tanh, masked RNE write, barrier.
#define STEP(T, X)                                                                 \
  {                                                                                \
    const int cb = (T) & 1, nb = cb ^ 1;                                           \
    f32x4 acc0, acc1;                                                              \
    _Pragma("unroll")                                                              \
    for (int q = 0; q < 4; ++q) {                                                  \
        acc0[q] = h2f_bits((u16)(X[q] & 0xffffu));                                 \
        acc1[q] = h2f_bits((u16)(X[q] >> 16));                                     \
    }                                                                              \
    {                                                                              \
        const unsigned toff = (unsigned)(((T) + 2 < SB) ? (T) + 2 : SB - 1) * HB;  \
        _Pragma("unroll")                                                          \
        for (int q = 0; q < 4; ++q)                                                \
            X[q] = *(const unsigned*)&xw[gbase[q] + toff];                         \
    }                                                                              \
    f16x8 Af[8];                                                                   \
    _Pragma("unroll")                                                              \
    for (int ks = 0; ks < 8; ++ks) {                                               \
        uint4 av = *(const uint4*)&H[cb][n & 7][ks * 32 + kg * 8];                 \
        Af[ks] = __builtin_bit_cast(f16x8, av);                                    \
    }                                                                              \
    _Pragma("unroll")                                                              \
    for (int ks = 0; ks < 8; ++ks) {                                               \
        acc0 = __builtin_amdgcn_mfma_f32_16x16x32_f16(Af[ks], Bf[0][ks], acc0, 0, 0, 0); \
        acc1 = __builtin_amdgcn_mfma_f32_16x16x32_f16(Af[ks], Bf[1][ks], acc1, 0, 0, 0); \
    }                                                                              \
    if (kg < 2) {                                                                  \
        _Pragma("unroll")                                                          \
        for (int q = 0; q < 4; ++q) {                                              \
            float th0 = tanh_fast(acc0[q]);                                        \
            float th1 = tanh_fast(acc1[q]);                                        \
            unsigned pk = (unsigned)f2h_bits(th0) | ((unsigned)f2h_bits(th1) << 16); \
            *(unsigned*)&H[nb][kg * 4 + q][pbase] = pk;                            \
        }                                                                          \
    }                                                                              \
    __syncthreads();                                                               \
  }

__global__ __launch_bounds__(512, 2) void rnn_scan_mfma(
    const u16* __restrict__ xw, const float* __restrict__ U,
    const float* __restrict__ V, const float* __restrict__ bV,
    float* __restrict__ out)
{
    __shared__ __align__(16) u16 H[2][ROWS][PITCH];   // double-buffered h (fp16), sigma order

    const int tid  = threadIdx.x;
    const int lane = tid & 63;
    const int w    = tid >> 6;            // wave 0..7, owns N-tiles 2w, 2w+1
    const int b0   = blockIdx.x * ROWS;

    {   // zero both H buffers (incl. pad)
        unsigned* hz = (unsigned*)H;
        for (int i = tid; i < 2 * ROWS * PITCH / 2; i += 512) hz[i] = 0u;
    }

    const int n  = lane & 15;             // A-m / B-n / D-col
    const int kg = lane >> 4;             // 0..3

    // ---- B-frag preload via sigma^-1: Bf[s][ks], tile nt=2w+s, col j_out=nt*16+n ----
    f16x8 Bf[2][8];
    #pragma unroll
    for (int s = 0; s < 2; ++s) {
        const int col = (2 * w + s) * 16 + n;
        #pragma unroll
        for (int ks = 0; ks < 8; ++ks) {
            union { f16x8 v; u16 h[8]; } tmp;
            #pragma unroll
            for (int e = 0; e < 8; ++e) {
                const int p = ks * 32 + kg * 8 + e;          // storage k
                const int jin = invsig(p);                   // actual contraction j
                tmp.h[e] = f2h_bits(U[(size_t)jin * HB + col]);
            }
            Bf[s][ks] = tmp.v;
        }
    }

    // ---- per-lane mapping: rows (kg&1)*4+q (kg>=2 duplicates), col pair 32w+2n ----
    const int pbase = 32 * w + 2 * n;
    unsigned gbase[4];
    unsigned XA[4], XB[4];
    #pragma unroll
    for (int q = 0; q < 4; ++q) {
        const int row = (kg & 1) * 4 + q;                    // dup rows for kg>=2
        gbase[q] = ((unsigned)(b0 + row) * SB) * HB + pbase;
        XA[q] = *(const unsigned*)&xw[gbase[q]];             // t = 0
        XB[q] = *(const unsigned*)&xw[gbase[q] + HB];        // t = 1
    }
    __syncthreads();

    for (int t = 0; t < SB; t += 2) {
        STEP(t,     XA);
        STEP(t + 1, XB);
    }

    // h output (f32 from fp16 H[0]; SB even -> final h in buffer 0)
    for (int i = tid; i < ROWS * HB; i += 512) {
        const int r = i >> 8, p = i & 255;
        out[BB * 2 + (size_t)(b0 + r) * HB + invsig(p)] = h2f_bits(H[0][r][p]);
    }

    // logits: first 128 threads = 8 rows x 16 partials
    if (tid < ROWS * 16) {
        const int r = tid >> 4, part = tid & 15;
        float s0 = 0.f, s1 = 0.f;
        #pragma unroll
        for (int i = 0; i < 16; ++i) {
            const int p = part * 16 + i;
            const int j = invsig(p);
            float hh = h2f_bits(H[0][r][p]);
            s0 = fmaf(hh, V[j * 2 + 0], s0);
            s1 = fmaf(hh, V[j * 2 + 1], s1);
        }
        #pragma unroll
        for (int o = 8; o > 0; o >>= 1) {
            s0 += __shfl_down(s0, o, 16);
            s1 += __shfl_down(s1, o, 16);
        }
        if (part == 0) {
            out[(size_t)(b0 + r) * 2 + 0] = s0 + bV[0];
            out[(size_t)(b0 + r) * 2 + 1] = s1 + bV[1];
        }
    }
}

extern "C" void kernel_launch(void* const* d_in, const int* in_sizes, int n_in,
                              void* d_out, int out_size, void* d_ws, size_t ws_size,
                              hipStream_t stream) {
    const int*   x   = (const int*)d_in[0];
    const float* emb = (const float*)d_in[1];
    const float* W   = (const float*)d_in[2];
    const float* U   = (const float*)d_in[3];
    const float* bU  = (const float*)d_in[4];
    const float* V   = (const float*)d_in[5];
    const float* bV  = (const float*)d_in[6];
    float* out = (float*)d_out;
    u16*   xw  = (u16*)d_ws;   // 64 MiB fp16 scratch, sigma-permuted columns

    embed_proj<<<BB * SB / TPB, 256, 0, stream>>>(x, emb, W, bU, xw);
    rnn_scan_mfma<<<BB / ROWS, 512, 0, stream>>>(xw, U, V, bV, out);
}

// Round 14
// 1188.355 us; speedup vs baseline: 1.3405x; 1.1665x over previous
//
#include <hip/hip_runtime.h>
#include <hip/hip_bf16.h>

// RNN_80848464380442: B=64, S=2048, V=50257, E=128, H=256, C=2 (f32 in/out, x int32)
// Stage 1: xw[tok][sig(j)] = bU[j] + sum_e emb[x]*W  (fp16 to ws, sigma-permuted cols)
// Stage 2: MFMA scan, 8 blocks x 8 batch rows, 8 waves x 2 N-tiles (512 thr, 2 w/SIMD).
//          D rows 8-15 duplicate rows 0-7 -> epilogue SPLIT across lane halves:
//          kg<2 lanes finish q=0,1 (rows rb,rb+1), kg>=2 finish q=2,3 -- every lane
//          4 tanh + 2 writes, no divergence, rows covered exactly once. C-init needs
//          only 2 xw words/lane (unused acc slots get dup values, discarded).
//          2-step prefetch ring; plain __syncthreads (asm barrier regressed R10-12).
// Stage 3: logits + h output post-loop from LDS.
// sigma: j = 32w+16s+n  ->  p = 32w+2n+s

#define HB 256
#define EB 128
#define SB 2048
#define BB 64
#define TPB 32
#define ROWS 8
#define PITCH 264   // u16/row = 528 B

typedef unsigned short u16;
typedef __attribute__((ext_vector_type(4))) float f32x4;
typedef __attribute__((ext_vector_type(8))) _Float16 f16x8;
typedef __attribute__((ext_vector_type(2))) __fp16 fp16x2_t;

__device__ __forceinline__ u16 f2h_bits(float f) {
    union { _Float16 h; u16 b; } x; x.h = (_Float16)f; return x.b;
}
__device__ __forceinline__ float h2f_bits(u16 b) {
    union { u16 b; _Float16 h; } x; x.b = b; return (float)x.h;
}
__device__ __forceinline__ float tanh_fast(float z) {
    float E = exp2f(z * 2.885390082f);             // e^(2z); tanh = 1 - 2/(e^2z + 1)
    return fmaf(-2.f, __builtin_amdgcn_rcpf(E + 1.f), 1.f);
}
__device__ __forceinline__ unsigned pkrtz(float a, float b) {
    fp16x2_t p = __builtin_amdgcn_cvt_pkrtz(a, b);
    return __builtin_bit_cast(unsigned, p);
}

__device__ __forceinline__ int sig(int j)    { return (j & 0xE0) | ((j & 15) << 1) | ((j >> 4) & 1); }
__device__ __forceinline__ int invsig(int p) { return (p & 0xE0) | ((p & 1) << 4) | ((p >> 1) & 15); }

// ---------------- Stage 1: embed + project (32 tokens per 256-thread block) --------
__global__ __launch_bounds__(256) void embed_proj(
    const int* __restrict__ x, const float* __restrict__ emb,
    const float* __restrict__ W, const float* __restrict__ bU,
    u16* __restrict__ xw)
{
    __shared__ __align__(16) float el[TPB][EB];   // 16 KB
    __shared__ int toks[TPB];

    const int tid = threadIdx.x;
    const long base = (long)blockIdx.x * TPB;

    if (tid < TPB) toks[tid] = x[base + tid];
    __syncthreads();

    for (int r = 0; r < TPB * EB / 256; ++r) {
        int i = tid + r * 256;
        int row = i >> 7, e = i & (EB - 1);
        int u = toks[row];
        el[row][e] = (u == 0) ? 0.f : emb[(size_t)u * EB + e];   // padding_idx=0
    }
    __syncthreads();

    const int j = tid;
    const int sj = sig(j);
    const float bu = bU[j];
    float acc[TPB];
    #pragma unroll
    for (int t = 0; t < TPB; ++t) acc[t] = bu;

    for (int e0 = 0; e0 < EB; e0 += 4) {
        float w0 = W[(e0 + 0) * HB + j];
        float w1 = W[(e0 + 1) * HB + j];
        float w2 = W[(e0 + 2) * HB + j];
        float w3 = W[(e0 + 3) * HB + j];
        #pragma unroll
        for (int t = 0; t < TPB; ++t) {
            float4 ev = *(const float4*)&el[t][e0];
            acc[t] = fmaf(ev.x, w0, acc[t]);
            acc[t] = fmaf(ev.y, w1, acc[t]);
            acc[t] = fmaf(ev.z, w2, acc[t]);
            acc[t] = fmaf(ev.w, w3, acc[t]);
        }
    }
    #pragma unroll
    for (int t = 0; t < TPB; ++t)
        xw[(base + t) * HB + sj] = f2h_bits(acc[t]);
}

// ---------------- Stage 2+3: MFMA scan, 8 blocks x 512 threads (8 waves) -----------
// STEP(T, X0, X1): X0/X1 hold step T's xw words for this lane's 2 owned rows.
// C-init dups them into both acc halves (unused half discarded at select).
#define STEP(T, X0, X1)                                                            \
  {                                                                                \
    const int cb = (T) & 1, nb = cb ^ 1;                                           \
    f32x4 acc0, acc1;                                                              \
    {                                                                              \
        float c00 = h2f_bits((u16)(X0 & 0xffffu));                                 \
        float c01 = h2f_bits((u16)(X0 >> 16));                                     \
        float c10 = h2f_bits((u16)(X1 & 0xffffu));                                 \
        float c11 = h2f_bits((u16)(X1 >> 16));                                     \
        acc0[0] = c00; acc0[2] = c00; acc0[1] = c10; acc0[3] = c10;                \
        acc1[0] = c01; acc1[2] = c01; acc1[1] = c11; acc1[3] = c11;                \
    }                                                                              \
    {                                                                              \
        const unsigned toff = (unsigned)(((T) + 2 < SB) ? (T) + 2 : SB - 1) * HB;  \
        X0 = *(const unsigned*)&xw[g0 + toff];                                     \
        X1 = *(const unsigned*)&xw[g1 + toff];                                     \
    }                                                                              \
    f16x8 Af[8];                                                                   \
    _Pragma("unroll")                                                              \
    for (int ks = 0; ks < 8; ++ks) {                                               \
        uint4 av = *(const uint4*)&H[cb][n & 7][ks * 32 + kg * 8];                 \
        Af[ks] = __builtin_bit_cast(f16x8, av);                                    \
    }                                                                              \
    _Pragma("unroll")                                                              \
    for (int ks = 0; ks < 8; ++ks) {                                               \
        acc0 = __builtin_amdgcn_mfma_f32_16x16x32_f16(Af[ks], Bf[0][ks], acc0, 0, 0, 0); \
        acc1 = __builtin_amdgcn_mfma_f32_16x16x32_f16(Af[ks], Bf[1][ks], acc1, 0, 0, 0); \
    }                                                                              \
    {                                                                              \
        float s00 = hi ? acc0[2] : acc0[0];   /* tile0, row rb   */                \
        float s01 = hi ? acc0[3] : acc0[1];   /* tile0, row rb+1 */                \
        float s10 = hi ? acc1[2] : acc1[0];   /* tile1, row rb   */                \
        float s11 = hi ? acc1[3] : acc1[1];   /* tile1, row rb+1 */                \
        unsigned pkA = pkrtz(tanh_fast(s00), tanh_fast(s10));                      \
        unsigned pkB = pkrtz(tanh_fast(s01), tanh_fast(s11));                      \
        u16* wp = Hflat + nb * (ROWS * PITCH) + wbase;                             \
        *(unsigned*)(wp)         = pkA;                                            \
        *(unsigned*)(wp + PITCH) = pkB;                                            \
    }                                                                              \
    __syncthreads();                                                               \
  }

__global__ __launch_bounds__(512, 2) void rnn_scan_mfma(
    const u16* __restrict__ xw, const float* __restrict__ U,
    const float* __restrict__ V, const float* __restrict__ bV,
    float* __restrict__ out)
{
    __shared__ __align__(16) u16 H[2][ROWS][PITCH];   // double-buffered h (fp16), sigma order

    const int tid  = threadIdx.x;
    const int lane = tid & 63;
    const int w    = tid >> 6;            // wave 0..7, owns N-tiles 2w, 2w+1
    const int b0   = blockIdx.x * ROWS;
    u16* Hflat = &H[0][0][0];

    {   // zero both H buffers (incl. pad)
        unsigned* hz = (unsigned*)Hflat;
        for (int i = tid; i < 2 * ROWS * PITCH / 2; i += 512) hz[i] = 0u;
    }

    const int n  = lane & 15;             // A-m / B-n / D-col
    const int kg = lane >> 4;             // 0..3
    const bool hi = kg >= 2;

    // ---- B-frag preload via sigma^-1: Bf[s][ks], tile nt=2w+s, col j_out=nt*16+n ----
    f16x8 Bf[2][8];
    #pragma unroll
    for (int s = 0; s < 2; ++s) {
        const int col = (2 * w + s) * 16 + n;
        #pragma unroll
        for (int ks = 0; ks < 8; ++ks) {
            union { f16x8 v; u16 h[8]; } tmp;
            #pragma unroll
            for (int e = 0; e < 8; ++e) {
                const int p = ks * 32 + kg * 8 + e;          // storage k
                const int jin = invsig(p);                   // actual contraction j
                tmp.h[e] = f2h_bits(U[(size_t)jin * HB + col]);
            }
            Bf[s][ks] = tmp.v;
        }
    }

    // ---- per-lane mapping: owns rows rb, rb+1 at col pair pbase = 32w+2n ----
    const int pbase = 32 * w + 2 * n;
    const int rb = (kg & 1) * 4 + (hi ? 2 : 0);   // kg 0,2,1,3 -> rows {0,1},{2,3},{4,5},{6,7}
    const int wbase = rb * PITCH + pbase;
    const unsigned g0 = ((unsigned)(b0 + rb) * SB) * HB + pbase;
    const unsigned g1 = g0 + SB * HB;
    unsigned XA0 = *(const unsigned*)&xw[g0];            // t = 0
    unsigned XA1 = *(const unsigned*)&xw[g1];
    unsigned XB0 = *(const unsigned*)&xw[g0 + HB];       // t = 1
    unsigned XB1 = *(const unsigned*)&xw[g1 + HB];
    __syncthreads();

    for (int t = 0; t < SB; t += 2) {
        STEP(t,     XA0, XA1);
        STEP(t + 1, XB0, XB1);
    }

    // h output (f32 from fp16 H[0]; SB even -> final h in buffer 0)
    for (int i = tid; i < ROWS * HB; i += 512) {
        const int r = i >> 8, p = i & 255;
        out[BB * 2 + (size_t)(b0 + r) * HB + invsig(p)] = h2f_bits(H[0][r][p]);
    }

    // logits: first 128 threads = 8 rows x 16 partials
    if (tid < ROWS * 16) {
        const int r = tid >> 4, part = tid & 15;
        float s0 = 0.f, s1 = 0.f;
        #pragma unroll
        for (int i = 0; i < 16; ++i) {
            const int p = part * 16 + i;
            const int j = invsig(p);
            float hh = h2f_bits(H[0][r][p]);
            s0 = fmaf(hh, V[j * 2 + 0], s0);
            s1 = fmaf(hh, V[j * 2 + 1], s1);
        }
        #pragma unroll
        for (int o = 8; o > 0; o >>= 1) {
            s0 += __shfl_down(s0, o, 16);
            s1 += __shfl_down(s1, o, 16);
        }
        if (part == 0) {
            out[(size_t)(b0 + r) * 2 + 0] = s0 + bV[0];
            out[(size_t)(b0 + r) * 2 + 1] = s1 + bV[1];
        }
    }
}

extern "C" void kernel_launch(void* const* d_in, const int* in_sizes, int n_in,
                              void* d_out, int out_size, void* d_ws, size_t ws_size,
                              hipStream_t stream) {
    const int*   x   = (const int*)d_in[0];
    const float* emb = (const float*)d_in[1];
    const float* W   = (const float*)d_in[2];
    const float* U   = (const float*)d_in[3];
    const float* bU  = (const float*)d_in[4];
    const float* V   = (const float*)d_in[5];
    const float* bV  = (const float*)d_in[6];
    float* out = (float*)d_out;
    u16*   xw  = (u16*)d_ws;   // 64 MiB fp16 scratch, sigma-permuted columns

    embed_proj<<<BB * SB / TPB, 256, 0, stream>>>(x, emb, W, bU, xw);
    rnn_scan_mfma<<<BB / ROWS, 512, 0, stream>>>(xw, U, V, bV, out);
}